// Round 7
// baseline (712.834 us; speedup 1.0000x reference)
//
#include <hip/hip_runtime.h>
#include <hip/hip_bf16.h>
#include <math.h>

#define B_    512
#define C_    2048
#define HW_   48      // 8*6 spatial
#define HID_  128
#define NATTR_ 51
#define EPS_  1e-5f

typedef float v4f __attribute__((ext_vector_type(4)));  // nontemporal-compatible

// ---------------------------------------------------------------------------
// Kernel A (v2): fused (body*A*face)->spatial max AND spatial mean of body.
// THREAD = ONE ROW (48 floats = 12 float4).  No LDS, no barrier, no
// divergent tail: reduction is fully in-lane; stores coalesced (lane l ->
// row r0+l).  Lane addresses stride 192B per instr, but consecutive q
// instructions consume every fetched 64B segment -> fetched == demand bytes.
// 12+12 nontemporal loads in two 6-deep batches: deep MLP, VGPR ~90.
// feat = body + front*gate (spatial-broadcast) => mean_spatial(feat) =
// mean_spatial(body) + front*gate: second body pass eliminated.
// ---------------------------------------------------------------------------
__global__ __launch_bounds__(256) void fused_pool(
    const float* __restrict__ body, const float* __restrict__ face,
    const float* __restrict__ A, float* __restrict__ pooled,
    float* __restrict__ bmean) {
  const int row = blockIdx.x * 256 + threadIdx.x;   // < 2^20
  const int base = row * 12;                        // float4 units, < 2^24
  const int abase = (row & (C_ - 1)) * 12;
  const v4f* __restrict__ b4 = (const v4f*)body;
  const v4f* __restrict__ f4 = (const v4f*)face;
  const v4f* __restrict__ a4 = (const v4f*)A;
  float m = -INFINITY, s = 0.f;
#pragma unroll
  for (int half = 0; half < 2; ++half) {
    v4f vb[6], vf[6], va[6];
#pragma unroll
    for (int q = 0; q < 6; ++q) {
      const int idx = half * 6 + q;
      vb[q] = __builtin_nontemporal_load(b4 + base + idx);
      vf[q] = __builtin_nontemporal_load(f4 + base + idx);
      va[q] = a4[abase + idx];
    }
#pragma unroll
    for (int q = 0; q < 6; ++q) {
      const float m0 = vb[q].x * va[q].x * vf[q].x;
      const float m1 = vb[q].y * va[q].y * vf[q].y;
      const float m2 = vb[q].z * va[q].z * vf[q].z;
      const float m3 = vb[q].w * va[q].w * vf[q].w;
      m = fmaxf(m, fmaxf(fmaxf(m0, m1), fmaxf(m2, m3)));
      s += (vb[q].x + vb[q].y) + (vb[q].z + vb[q].w);
    }
  }
  pooled[row] = m;
  bmean[row] = s * (1.0f / 48.0f);
}

// ---------------------------------------------------------------------------
// Kernel W: transpose W2 [2048c][128k] -> W2T [128k][2048c] (once, ~1MB).
// 64x64 tiles, LDS pad 65 -> conflict-free both phases.  Earns its keep:
// it converts mlp2's per-lane W2-row walks (16x L2 segment overfetch) into
// fully coalesced column reads.
// ---------------------------------------------------------------------------
__global__ __launch_bounds__(256) void w2t_kernel(
    const float* __restrict__ W2, float* __restrict__ W2T) {
  __shared__ float tile[64][65];
  const int t = threadIdx.x;
  const int kt = blockIdx.x & 1, ct = blockIdx.x >> 1;
  const int c0 = ct * 64, k0 = kt * 64;
  const int x = t & 63, y4 = t >> 6;
#pragma unroll
  for (int i = 0; i < 16; ++i) {
    const int r = y4 + 4 * i;
    tile[r][x] = W2[(c0 + r) * HID_ + k0 + x];   // lanes along k: coalesced
  }
  __syncthreads();
#pragma unroll
  for (int i = 0; i < 16; ++i) {
    const int kk = y4 + 4 * i;
    W2T[(k0 + kk) * C_ + c0 + x] = tile[x][kk];  // lds stride 65: no conflict
  }
}

// ---------------------------------------------------------------------------
// Kernel B1: h = relu(pooled @ W1^T + b1).  K along lanes (coalesced 256B),
// wave tile = 4s x 8o, shfl reduce.  grid 512 blocks x 4 waves.
// ---------------------------------------------------------------------------
__global__ __launch_bounds__(256) void mlp1(
    const float* __restrict__ pooled, const float* __restrict__ W1,
    const float* __restrict__ b1, float* __restrict__ h) {
  const int t = threadIdx.x;
  const int lane = t & 63;
  const int w = t >> 6;
  const int s0 = (blockIdx.x >> 2) * 4;
  const int o0 = ((blockIdx.x & 3) * 4 + w) * 8;
  float acc[4][8] = {};
  const float* __restrict__ pb = pooled + lane;
  const float* __restrict__ wb = W1 + lane;
#pragma unroll 2
  for (int kc = 0; kc < 32; ++kc) {
    const int k = kc * 64;
    float p[4], wv[8];
#pragma unroll
    for (int i = 0; i < 4; ++i) p[i] = pb[(s0 + i) * C_ + k];
#pragma unroll
    for (int j = 0; j < 8; ++j) wv[j] = wb[(o0 + j) * C_ + k];
#pragma unroll
    for (int i = 0; i < 4; ++i)
#pragma unroll
      for (int j = 0; j < 8; ++j) acc[i][j] += p[i] * wv[j];
  }
#pragma unroll
  for (int d = 32; d >= 1; d >>= 1)
#pragma unroll
    for (int i = 0; i < 4; ++i)
#pragma unroll
      for (int j = 0; j < 8; ++j) acc[i][j] += __shfl_down(acc[i][j], d);
  if (lane == 0) {
#pragma unroll
    for (int i = 0; i < 4; ++i)
#pragma unroll
      for (int j = 0; j < 8; ++j)
        h[(s0 + i) * HID_ + o0 + j] = fmaxf(acc[i][j] + b1[o0 + j], 0.f);
  }
}

// ---------------------------------------------------------------------------
// Kernel B2: gap = bmean + front*sigmoid(h @ W2^T + b2), via W2T.
// Thread = one c, 4 samples.  W2T column reads coalesced (L2-resident);
// h reads wave-uniform float4 broadcasts.  No LDS.
// grid = 8 c-chunks x 128 s-groups = 1024 blocks.
// ---------------------------------------------------------------------------
__global__ __launch_bounds__(256) void mlp2_t(
    const float* __restrict__ h, const float* __restrict__ W2T,
    const float* __restrict__ b2, const float* __restrict__ bmean,
    const int* __restrict__ pose, float* __restrict__ gap) {
  const int t = threadIdx.x;
  const int c = (blockIdx.x & 7) * 256 + t;
  const int s0 = (blockIdx.x >> 3) * 4;
  float acc[4] = {};
  for (int kq = 0; kq < 32; ++kq) {
    float wv[4];
#pragma unroll
    for (int d = 0; d < 4; ++d) wv[d] = W2T[(4 * kq + d) * C_ + c];
#pragma unroll
    for (int i = 0; i < 4; ++i) {
      const float4 hv = *(const float4*)&h[(s0 + i) * HID_ + 4 * kq];
      acc[i] += hv.x * wv[0] + hv.y * wv[1] + hv.z * wv[2] + hv.w * wv[3];
    }
  }
  const float bias = b2[c];
#pragma unroll
  for (int i = 0; i < 4; ++i) {
    const int s = s0 + i;
    const float fr = (pose[s] == 1) ? 1.f : 0.f;
    const float g = 1.f / (1.f + expf(-(acc[i] + bias)));
    gap[s * C_ + c] = bmean[s * C_ + c] + fr * g;
  }
}

// ---------------------------------------------------------------------------
// Kernel B3: z = gap @ Wl^T + bl.  K along lanes, wave tile = 2s x 13o.
// grid 256 blocks x 4 waves (o covered by 4x13=52 slots, last clamped).
// ---------------------------------------------------------------------------
__global__ __launch_bounds__(256) void logits_k(
    const float* __restrict__ gap, const float* __restrict__ Wl,
    const float* __restrict__ bl, float* __restrict__ z) {
  const int t = threadIdx.x;
  const int lane = t & 63;
  const int w = t >> 6;
  const int s0 = blockIdx.x * 2;
  const int o0 = w * 13;
  float acc[2][13] = {};
  const float* __restrict__ gb = gap + lane;
  const float* __restrict__ wb = Wl + lane;
  for (int kc = 0; kc < 32; ++kc) {
    const int k = kc * 64;
    float p[2], wv[13];
#pragma unroll
    for (int i = 0; i < 2; ++i) p[i] = gb[(s0 + i) * C_ + k];
#pragma unroll
    for (int j = 0; j < 13; ++j) {
      const int o = o0 + j;
      const int orow = (o < NATTR_) ? o : (NATTR_ - 1);
      wv[j] = wb[orow * C_ + k];
    }
#pragma unroll
    for (int i = 0; i < 2; ++i)
#pragma unroll
      for (int j = 0; j < 13; ++j) acc[i][j] += p[i] * wv[j];
  }
#pragma unroll
  for (int d = 32; d >= 1; d >>= 1)
#pragma unroll
    for (int i = 0; i < 2; ++i)
#pragma unroll
      for (int j = 0; j < 13; ++j) acc[i][j] += __shfl_down(acc[i][j], d);
  if (lane == 0) {
#pragma unroll
    for (int i = 0; i < 2; ++i)
#pragma unroll
      for (int j = 0; j < 13; ++j) {
        const int o = o0 + j;
        if (o < NATTR_)
          z[(s0 + i) * NATTR_ + o] = acc[i][j] + bl[o];
      }
  }
}

// ---------------------------------------------------------------------------
// Kernel C: BatchNorm1d (batch stats, biased variance).
// ---------------------------------------------------------------------------
__global__ __launch_bounds__(512) void bn_kernel(
    const float* __restrict__ z, const float* __restrict__ gamma,
    const float* __restrict__ beta, float* __restrict__ out) {
  const int c = blockIdx.x;
  const int t = threadIdx.x;
  const float v = z[t * NATTR_ + c];
  float a = v, b = v * v;
#pragma unroll
  for (int off = 32; off; off >>= 1) {
    a += __shfl_down(a, off);
    b += __shfl_down(b, off);
  }
  __shared__ float s1[8], s2[8];
  const int w = t >> 6;
  if ((t & 63) == 0) { s1[w] = a; s2[w] = b; }
  __syncthreads();
  __shared__ float mu_s, inv_s;
  if (t == 0) {
    float S = 0.f, Q = 0.f;
#pragma unroll
    for (int i = 0; i < 8; ++i) { S += s1[i]; Q += s2[i]; }
    const float m = S * (1.0f / B_);
    const float var = Q * (1.0f / B_) - m * m;
    mu_s = m;
    inv_s = 1.0f / sqrtf(var + EPS_);
  }
  __syncthreads();
  out[t * NATTR_ + c] = gamma[c] * (v - mu_s) * inv_s + beta[c];
}

// ---------------------------------------------------------------------------
extern "C" void kernel_launch(void* const* d_in, const int* in_sizes, int n_in,
                              void* d_out, int out_size, void* d_ws,
                              size_t ws_size, hipStream_t stream) {
  const float* body = (const float*)d_in[0];
  const float* face = (const float*)d_in[1];
  const int* pose = (const int*)d_in[2];
  const float* A = (const float*)d_in[3];
  const float* W1 = (const float*)d_in[4];
  const float* b1 = (const float*)d_in[5];
  const float* W2 = (const float*)d_in[6];
  const float* b2 = (const float*)d_in[7];
  const float* Wl = (const float*)d_in[8];
  const float* bl = (const float*)d_in[9];
  const float* gamma = (const float*)d_in[10];
  const float* beta = (const float*)d_in[11];
  float* out = (float*)d_out;

  float* ws = (float*)d_ws;
  float* pooled = ws;                       // [512][2048]
  float* bmean = pooled + B_ * C_;          // [512][2048]
  float* h = bmean + B_ * C_;               // [512][128]
  float* gap = h + B_ * HID_;               // [512][2048]
  float* z = gap + B_ * C_;                 // [512][51]
  float* W2T = z + B_ * NATTR_;             // [128][2048]

  fused_pool<<<dim3(4096), dim3(256), 0, stream>>>(body, face, A, pooled,
                                                   bmean);
  w2t_kernel<<<dim3(64), dim3(256), 0, stream>>>(W2, W2T);
  mlp1<<<dim3(512), dim3(256), 0, stream>>>(pooled, W1, b1, h);
  mlp2_t<<<dim3(1024), dim3(256), 0, stream>>>(h, W2T, b2, bmean, pose, gap);
  logits_k<<<dim3(256), dim3(256), 0, stream>>>(gap, Wl, bl, z);
  bn_kernel<<<dim3(NATTR_), dim3(512), 0, stream>>>(z, gamma, beta, out);
}

// Round 8
// 527.273 us; speedup vs baseline: 1.3519x; 1.3519x over previous
//
#include <hip/hip_runtime.h>
#include <hip/hip_bf16.h>
#include <math.h>

#define B_    512
#define C_    2048
#define HW_   48      // 8*6 spatial
#define HID_  128
#define NATTR_ 51
#define EPS_  1e-5f

// ---------------------------------------------------------------------------
// Kernel A (v3): fused (body*A*face)->spatial max AND spatial mean of body.
// THREAD = ONE ROW (48 floats = 12 float4), PLAIN loads (no nontemporal!).
// R7 lesson: NT + 192B-strided lanes = 2.3x HBM over-fetch (925MB) because
// NT bypasses L1 and each 64B line is refetched for q=1..3.  With normal
// loads, q=0 fetches the line and q=1..3 hit L1 -> fetched == demand.
// No LDS, no barrier, no divergent tail; stores coalesced.
// feat = body + front*gate (spatial-broadcast) => mean_spatial(feat) =
// mean_spatial(body) + front*gate: second body pass eliminated.
// ---------------------------------------------------------------------------
__global__ __launch_bounds__(256) void fused_pool(
    const float* __restrict__ body, const float* __restrict__ face,
    const float* __restrict__ A, float* __restrict__ pooled,
    float* __restrict__ bmean) {
  const int row = blockIdx.x * 256 + threadIdx.x;   // < 2^20
  const int base = row * 12;                        // float4 units, < 2^24
  const int abase = (row & (C_ - 1)) * 12;
  const float4* __restrict__ b4 = (const float4*)body;
  const float4* __restrict__ f4 = (const float4*)face;
  const float4* __restrict__ a4 = (const float4*)A;
  float m = -INFINITY, s = 0.f;
#pragma unroll
  for (int half = 0; half < 2; ++half) {
    float4 vb[6], vf[6], va[6];
#pragma unroll
    for (int q = 0; q < 6; ++q) {
      const int idx = half * 6 + q;
      vb[q] = b4[base + idx];
      vf[q] = f4[base + idx];
      va[q] = a4[abase + idx];
    }
#pragma unroll
    for (int q = 0; q < 6; ++q) {
      const float m0 = vb[q].x * va[q].x * vf[q].x;
      const float m1 = vb[q].y * va[q].y * vf[q].y;
      const float m2 = vb[q].z * va[q].z * vf[q].z;
      const float m3 = vb[q].w * va[q].w * vf[q].w;
      m = fmaxf(m, fmaxf(fmaxf(m0, m1), fmaxf(m2, m3)));
      s += (vb[q].x + vb[q].y) + (vb[q].z + vb[q].w);
    }
  }
  pooled[row] = m;
  bmean[row] = s * (1.0f / 48.0f);
}

// ---------------------------------------------------------------------------
// Kernel W: transpose W2 [2048c][128k] -> W2T [128k][2048c] (once, ~1MB).
// 64x64 tiles, LDS pad 65 -> conflict-free both phases.
// ---------------------------------------------------------------------------
__global__ __launch_bounds__(256) void w2t_kernel(
    const float* __restrict__ W2, float* __restrict__ W2T) {
  __shared__ float tile[64][65];
  const int t = threadIdx.x;
  const int kt = blockIdx.x & 1, ct = blockIdx.x >> 1;
  const int c0 = ct * 64, k0 = kt * 64;
  const int x = t & 63, y4 = t >> 6;
#pragma unroll
  for (int i = 0; i < 16; ++i) {
    const int r = y4 + 4 * i;
    tile[r][x] = W2[(c0 + r) * HID_ + k0 + x];   // lanes along k: coalesced
  }
  __syncthreads();
#pragma unroll
  for (int i = 0; i < 16; ++i) {
    const int kk = y4 + 4 * i;
    W2T[(k0 + kk) * C_ + c0 + x] = tile[x][kk];  // lds stride 65: no conflict
  }
}

// ---------------------------------------------------------------------------
// Kernel B1: h = relu(pooled @ W1^T + b1).  K along lanes (coalesced 256B),
// wave tile = 4s x 8o, shfl reduce.  grid 512 blocks x 4 waves.
// ---------------------------------------------------------------------------
__global__ __launch_bounds__(256) void mlp1(
    const float* __restrict__ pooled, const float* __restrict__ W1,
    const float* __restrict__ b1, float* __restrict__ h) {
  const int t = threadIdx.x;
  const int lane = t & 63;
  const int w = t >> 6;
  const int s0 = (blockIdx.x >> 2) * 4;
  const int o0 = ((blockIdx.x & 3) * 4 + w) * 8;
  float acc[4][8] = {};
  const float* __restrict__ pb = pooled + lane;
  const float* __restrict__ wb = W1 + lane;
#pragma unroll 2
  for (int kc = 0; kc < 32; ++kc) {
    const int k = kc * 64;
    float p[4], wv[8];
#pragma unroll
    for (int i = 0; i < 4; ++i) p[i] = pb[(s0 + i) * C_ + k];
#pragma unroll
    for (int j = 0; j < 8; ++j) wv[j] = wb[(o0 + j) * C_ + k];
#pragma unroll
    for (int i = 0; i < 4; ++i)
#pragma unroll
      for (int j = 0; j < 8; ++j) acc[i][j] += p[i] * wv[j];
  }
#pragma unroll
  for (int d = 32; d >= 1; d >>= 1)
#pragma unroll
    for (int i = 0; i < 4; ++i)
#pragma unroll
      for (int j = 0; j < 8; ++j) acc[i][j] += __shfl_down(acc[i][j], d);
  if (lane == 0) {
#pragma unroll
    for (int i = 0; i < 4; ++i)
#pragma unroll
      for (int j = 0; j < 8; ++j)
        h[(s0 + i) * HID_ + o0 + j] = fmaxf(acc[i][j] + b1[o0 + j], 0.f);
  }
}

// ---------------------------------------------------------------------------
// Kernel B2: gap = bmean + front*sigmoid(h @ W2^T + b2), via W2T.
// Thread = one c, 4 samples.  W2T column reads coalesced (L2-resident);
// h reads wave-uniform float4 broadcasts.  No LDS.
// grid = 8 c-chunks x 128 s-groups = 1024 blocks.
// ---------------------------------------------------------------------------
__global__ __launch_bounds__(256) void mlp2_t(
    const float* __restrict__ h, const float* __restrict__ W2T,
    const float* __restrict__ b2, const float* __restrict__ bmean,
    const int* __restrict__ pose, float* __restrict__ gap) {
  const int t = threadIdx.x;
  const int c = (blockIdx.x & 7) * 256 + t;
  const int s0 = (blockIdx.x >> 3) * 4;
  float acc[4] = {};
  for (int kq = 0; kq < 32; ++kq) {
    float wv[4];
#pragma unroll
    for (int d = 0; d < 4; ++d) wv[d] = W2T[(4 * kq + d) * C_ + c];
#pragma unroll
    for (int i = 0; i < 4; ++i) {
      const float4 hv = *(const float4*)&h[(s0 + i) * HID_ + 4 * kq];
      acc[i] += hv.x * wv[0] + hv.y * wv[1] + hv.z * wv[2] + hv.w * wv[3];
    }
  }
  const float bias = b2[c];
#pragma unroll
  for (int i = 0; i < 4; ++i) {
    const int s = s0 + i;
    const float fr = (pose[s] == 1) ? 1.f : 0.f;
    const float g = 1.f / (1.f + expf(-(acc[i] + bias)));
    gap[s * C_ + c] = bmean[s * C_ + c] + fr * g;
  }
}

// ---------------------------------------------------------------------------
// Kernel B3: z = gap @ Wl^T + bl.  K along lanes, wave tile = 2s x 13o.
// grid 256 blocks x 4 waves (o covered by 4x13=52 slots, last clamped).
// ---------------------------------------------------------------------------
__global__ __launch_bounds__(256) void logits_k(
    const float* __restrict__ gap, const float* __restrict__ Wl,
    const float* __restrict__ bl, float* __restrict__ z) {
  const int t = threadIdx.x;
  const int lane = t & 63;
  const int w = t >> 6;
  const int s0 = blockIdx.x * 2;
  const int o0 = w * 13;
  float acc[2][13] = {};
  const float* __restrict__ gb = gap + lane;
  const float* __restrict__ wb = Wl + lane;
  for (int kc = 0; kc < 32; ++kc) {
    const int k = kc * 64;
    float p[2], wv[13];
#pragma unroll
    for (int i = 0; i < 2; ++i) p[i] = gb[(s0 + i) * C_ + k];
#pragma unroll
    for (int j = 0; j < 13; ++j) {
      const int o = o0 + j;
      const int orow = (o < NATTR_) ? o : (NATTR_ - 1);
      wv[j] = wb[orow * C_ + k];
    }
#pragma unroll
    for (int i = 0; i < 2; ++i)
#pragma unroll
      for (int j = 0; j < 13; ++j) acc[i][j] += p[i] * wv[j];
  }
#pragma unroll
  for (int d = 32; d >= 1; d >>= 1)
#pragma unroll
    for (int i = 0; i < 2; ++i)
#pragma unroll
      for (int j = 0; j < 13; ++j) acc[i][j] += __shfl_down(acc[i][j], d);
  if (lane == 0) {
#pragma unroll
    for (int i = 0; i < 2; ++i)
#pragma unroll
      for (int j = 0; j < 13; ++j) {
        const int o = o0 + j;
        if (o < NATTR_)
          z[(s0 + i) * NATTR_ + o] = acc[i][j] + bl[o];
      }
  }
}

// ---------------------------------------------------------------------------
// Kernel C: BatchNorm1d (batch stats, biased variance).
// ---------------------------------------------------------------------------
__global__ __launch_bounds__(512) void bn_kernel(
    const float* __restrict__ z, const float* __restrict__ gamma,
    const float* __restrict__ beta, float* __restrict__ out) {
  const int c = blockIdx.x;
  const int t = threadIdx.x;
  const float v = z[t * NATTR_ + c];
  float a = v, b = v * v;
#pragma unroll
  for (int off = 32; off; off >>= 1) {
    a += __shfl_down(a, off);
    b += __shfl_down(b, off);
  }
  __shared__ float s1[8], s2[8];
  const int w = t >> 6;
  if ((t & 63) == 0) { s1[w] = a; s2[w] = b; }
  __syncthreads();
  __shared__ float mu_s, inv_s;
  if (t == 0) {
    float S = 0.f, Q = 0.f;
#pragma unroll
    for (int i = 0; i < 8; ++i) { S += s1[i]; Q += s2[i]; }
    const float m = S * (1.0f / B_);
    const float var = Q * (1.0f / B_) - m * m;
    mu_s = m;
    inv_s = 1.0f / sqrtf(var + EPS_);
  }
  __syncthreads();
  out[t * NATTR_ + c] = gamma[c] * (v - mu_s) * inv_s + beta[c];
}

// ---------------------------------------------------------------------------
extern "C" void kernel_launch(void* const* d_in, const int* in_sizes, int n_in,
                              void* d_out, int out_size, void* d_ws,
                              size_t ws_size, hipStream_t stream) {
  const float* body = (const float*)d_in[0];
  const float* face = (const float*)d_in[1];
  const int* pose = (const int*)d_in[2];
  const float* A = (const float*)d_in[3];
  const float* W1 = (const float*)d_in[4];
  const float* b1 = (const float*)d_in[5];
  const float* W2 = (const float*)d_in[6];
  const float* b2 = (const float*)d_in[7];
  const float* Wl = (const float*)d_in[8];
  const float* bl = (const float*)d_in[9];
  const float* gamma = (const float*)d_in[10];
  const float* beta = (const float*)d_in[11];
  float* out = (float*)d_out;

  float* ws = (float*)d_ws;
  float* pooled = ws;                       // [512][2048]
  float* bmean = pooled + B_ * C_;          // [512][2048]
  float* h = bmean + B_ * C_;               // [512][128]
  float* gap = h + B_ * HID_;               // [512][2048]
  float* z = gap + B_ * C_;                 // [512][51]
  float* W2T = z + B_ * NATTR_;             // [128][2048]

  fused_pool<<<dim3(4096), dim3(256), 0, stream>>>(body, face, A, pooled,
                                                   bmean);
  w2t_kernel<<<dim3(64), dim3(256), 0, stream>>>(W2, W2T);
  mlp1<<<dim3(512), dim3(256), 0, stream>>>(pooled, W1, b1, h);
  mlp2_t<<<dim3(1024), dim3(256), 0, stream>>>(h, W2T, b2, bmean, pose, gap);
  logits_k<<<dim3(256), dim3(256), 0, stream>>>(gap, Wl, bl, z);
  bn_kernel<<<dim3(NATTR_), dim3(512), 0, stream>>>(z, gamma, beta, out);
}

// Round 10
// 435.847 us; speedup vs baseline: 1.6355x; 1.2098x over previous
//
#include <hip/hip_runtime.h>
#include <hip/hip_bf16.h>
#include <math.h>

#define B_    512
#define C_    2048
#define HW_   48      // 8*6 spatial
#define HID_  128
#define NATTR_ 51
#define EPS_  1e-5f

typedef float v4f __attribute__((ext_vector_type(4)));  // nontemporal-compatible

// ---------------------------------------------------------------------------
// Kernel A (v4): fused (body*A*face)->spatial max AND spatial mean of body.
// COALESCED layout (R2/R5 structure — empirically beats per-row by 1.5-3x):
// 128 rows/block, 256 threads, lane-contiguous float4 so every wave
// instruction is one 1KB transaction.  NT loads kept: on fully-consumed
// lines they are harmless (R5) and skip L3 pollution; R7 showed NT is only
// toxic combined with strided lanes.  ONE 18-deep load batch (6 body + 6
// face + 6 A in flight) -- this round's single variable vs R5's 2x9.
// LDS pitch 13 -> conflict-free reduce.
// feat = body + front*gate (spatial-broadcast) => mean_spatial(feat) =
// mean_spatial(body) + front*gate: second body pass eliminated.
// ---------------------------------------------------------------------------
__global__ __launch_bounds__(256) void fused_pool(
    const float* __restrict__ body, const float* __restrict__ face,
    const float* __restrict__ A, float* __restrict__ pooled,
    float* __restrict__ bmean) {
  __shared__ float smax[128 * 13];
  __shared__ float ssum[128 * 13];
  const int t = threadIdx.x;
  const int base_f4 = blockIdx.x * 1536;     // 8192*1536 < 2^31
  const int a_base = (blockIdx.x & 15) * 1536;
  const v4f* __restrict__ b4 = (const v4f*)body;
  const v4f* __restrict__ f4 = (const v4f*)face;
  const v4f* __restrict__ a4 = (const v4f*)A;
  v4f vb[6], vf[6], va[6];
#pragma unroll
  for (int j = 0; j < 6; ++j) {
    const int fl = t + 256 * j;
    vb[j] = __builtin_nontemporal_load(b4 + base_f4 + fl);
    vf[j] = __builtin_nontemporal_load(f4 + base_f4 + fl);
    va[j] = a4[a_base + fl];
  }
#pragma unroll
  for (int j = 0; j < 6; ++j) {
    const int fl = t + 256 * j;
    const int rl = fl / 12, p = fl % 12;
    const float m0 = vb[j].x * va[j].x * vf[j].x;
    const float m1 = vb[j].y * va[j].y * vf[j].y;
    const float m2 = vb[j].z * va[j].z * vf[j].z;
    const float m3 = vb[j].w * va[j].w * vf[j].w;
    smax[rl * 13 + p] = fmaxf(fmaxf(m0, m1), fmaxf(m2, m3));
    ssum[rl * 13 + p] = (vb[j].x + vb[j].y) + (vb[j].z + vb[j].w);
  }
  __syncthreads();
  if (t < 128) {
    float m = -INFINITY, s = 0.f;
#pragma unroll
    for (int p = 0; p < 12; ++p) {
      m = fmaxf(m, smax[t * 13 + p]);
      s += ssum[t * 13 + p];
    }
    const int row = blockIdx.x * 128 + t;
    pooled[row] = m;
    bmean[row] = s * (1.0f / 48.0f);
  }
}

// ---------------------------------------------------------------------------
// Kernel W: transpose W2 [2048c][128k] -> W2T [128k][2048c] (once, ~1MB).
// 64x64 tiles, LDS pad 65 -> conflict-free both phases.
// ---------------------------------------------------------------------------
__global__ __launch_bounds__(256) void w2t_kernel(
    const float* __restrict__ W2, float* __restrict__ W2T) {
  __shared__ float tile[64][65];
  const int t = threadIdx.x;
  const int kt = blockIdx.x & 1, ct = blockIdx.x >> 1;
  const int c0 = ct * 64, k0 = kt * 64;
  const int x = t & 63, y4 = t >> 6;
#pragma unroll
  for (int i = 0; i < 16; ++i) {
    const int r = y4 + 4 * i;
    tile[r][x] = W2[(c0 + r) * HID_ + k0 + x];   // lanes along k: coalesced
  }
  __syncthreads();
#pragma unroll
  for (int i = 0; i < 16; ++i) {
    const int kk = y4 + 4 * i;
    W2T[(k0 + kk) * C_ + c0 + x] = tile[x][kk];  // lds stride 65: no conflict
  }
}

// ---------------------------------------------------------------------------
// Kernel B1: h = relu(pooled @ W1^T + b1).  K along lanes (coalesced 256B),
// wave tile = 4s x 8o, shfl reduce.  grid 512 blocks x 4 waves.
// ---------------------------------------------------------------------------
__global__ __launch_bounds__(256) void mlp1(
    const float* __restrict__ pooled, const float* __restrict__ W1,
    const float* __restrict__ b1, float* __restrict__ h) {
  const int t = threadIdx.x;
  const int lane = t & 63;
  const int w = t >> 6;
  const int s0 = (blockIdx.x >> 2) * 4;
  const int o0 = ((blockIdx.x & 3) * 4 + w) * 8;
  float acc[4][8] = {};
  const float* __restrict__ pb = pooled + lane;
  const float* __restrict__ wb = W1 + lane;
#pragma unroll 2
  for (int kc = 0; kc < 32; ++kc) {
    const int k = kc * 64;
    float p[4], wv[8];
#pragma unroll
    for (int i = 0; i < 4; ++i) p[i] = pb[(s0 + i) * C_ + k];
#pragma unroll
    for (int j = 0; j < 8; ++j) wv[j] = wb[(o0 + j) * C_ + k];
#pragma unroll
    for (int i = 0; i < 4; ++i)
#pragma unroll
      for (int j = 0; j < 8; ++j) acc[i][j] += p[i] * wv[j];
  }
#pragma unroll
  for (int d = 32; d >= 1; d >>= 1)
#pragma unroll
    for (int i = 0; i < 4; ++i)
#pragma unroll
      for (int j = 0; j < 8; ++j) acc[i][j] += __shfl_down(acc[i][j], d);
  if (lane == 0) {
#pragma unroll
    for (int i = 0; i < 4; ++i)
#pragma unroll
      for (int j = 0; j < 8; ++j)
        h[(s0 + i) * HID_ + o0 + j] = fmaxf(acc[i][j] + b1[o0 + j], 0.f);
  }
}

// ---------------------------------------------------------------------------
// Kernel B2: gap = bmean + front*sigmoid(h @ W2^T + b2), via W2T.
// Thread = one c, 4 samples.  W2T column reads coalesced (L2-resident);
// h reads wave-uniform float4 broadcasts.  No LDS.
// grid = 8 c-chunks x 128 s-groups = 1024 blocks.
// ---------------------------------------------------------------------------
__global__ __launch_bounds__(256) void mlp2_t(
    const float* __restrict__ h, const float* __restrict__ W2T,
    const float* __restrict__ b2, const float* __restrict__ bmean,
    const int* __restrict__ pose, float* __restrict__ gap) {
  const int t = threadIdx.x;
  const int c = (blockIdx.x & 7) * 256 + t;
  const int s0 = (blockIdx.x >> 3) * 4;
  float acc[4] = {};
  for (int kq = 0; kq < 32; ++kq) {
    float wv[4];
#pragma unroll
    for (int d = 0; d < 4; ++d) wv[d] = W2T[(4 * kq + d) * C_ + c];
#pragma unroll
    for (int i = 0; i < 4; ++i) {
      const float4 hv = *(const float4*)&h[(s0 + i) * HID_ + 4 * kq];
      acc[i] += hv.x * wv[0] + hv.y * wv[1] + hv.z * wv[2] + hv.w * wv[3];
    }
  }
  const float bias = b2[c];
#pragma unroll
  for (int i = 0; i < 4; ++i) {
    const int s = s0 + i;
    const float fr = (pose[s] == 1) ? 1.f : 0.f;
    const float g = 1.f / (1.f + expf(-(acc[i] + bias)));
    gap[s * C_ + c] = bmean[s * C_ + c] + fr * g;
  }
}

// ---------------------------------------------------------------------------
// Kernel B3: z = gap @ Wl^T + bl.  K along lanes, wave tile = 2s x 13o.
// grid 256 blocks x 4 waves (o covered by 4x13=52 slots, last clamped).
// ---------------------------------------------------------------------------
__global__ __launch_bounds__(256) void logits_k(
    const float* __restrict__ gap, const float* __restrict__ Wl,
    const float* __restrict__ bl, float* __restrict__ z) {
  const int t = threadIdx.x;
  const int lane = t & 63;
  const int w = t >> 6;
  const int s0 = blockIdx.x * 2;
  const int o0 = w * 13;
  float acc[2][13] = {};
  const float* __restrict__ gb = gap + lane;
  const float* __restrict__ wb = Wl + lane;
  for (int kc = 0; kc < 32; ++kc) {
    const int k = kc * 64;
    float p[2], wv[13];
#pragma unroll
    for (int i = 0; i < 2; ++i) p[i] = gb[(s0 + i) * C_ + k];
#pragma unroll
    for (int j = 0; j < 13; ++j) {
      const int o = o0 + j;
      const int orow = (o < NATTR_) ? o : (NATTR_ - 1);
      wv[j] = wb[orow * C_ + k];
    }
#pragma unroll
    for (int i = 0; i < 2; ++i)
#pragma unroll
      for (int j = 0; j < 13; ++j) acc[i][j] += p[i] * wv[j];
  }
#pragma unroll
  for (int d = 32; d >= 1; d >>= 1)
#pragma unroll
    for (int i = 0; i < 2; ++i)
#pragma unroll
      for (int j = 0; j < 13; ++j) acc[i][j] += __shfl_down(acc[i][j], d);
  if (lane == 0) {
#pragma unroll
    for (int i = 0; i < 2; ++i)
#pragma unroll
      for (int j = 0; j < 13; ++j) {
        const int o = o0 + j;
        if (o < NATTR_)
          z[(s0 + i) * NATTR_ + o] = acc[i][j] + bl[o];
      }
  }
}

// ---------------------------------------------------------------------------
// Kernel C: BatchNorm1d (batch stats, biased variance).
// ---------------------------------------------------------------------------
__global__ __launch_bounds__(512) void bn_kernel(
    const float* __restrict__ z, const float* __restrict__ gamma,
    const float* __restrict__ beta, float* __restrict__ out) {
  const int c = blockIdx.x;
  const int t = threadIdx.x;
  const float v = z[t * NATTR_ + c];
  float a = v, b = v * v;
#pragma unroll
  for (int off = 32; off; off >>= 1) {
    a += __shfl_down(a, off);
    b += __shfl_down(b, off);
  }
  __shared__ float s1[8], s2[8];
  const int w = t >> 6;
  if ((t & 63) == 0) { s1[w] = a; s2[w] = b; }
  __syncthreads();
  __shared__ float mu_s, inv_s;
  if (t == 0) {
    float S = 0.f, Q = 0.f;
#pragma unroll
    for (int i = 0; i < 8; ++i) { S += s1[i]; Q += s2[i]; }
    const float m = S * (1.0f / B_);
    const float var = Q * (1.0f / B_) - m * m;
    mu_s = m;
    inv_s = 1.0f / sqrtf(var + EPS_);
  }
  __syncthreads();
  out[t * NATTR_ + c] = gamma[c] * (v - mu_s) * inv_s + beta[c];
}

// ---------------------------------------------------------------------------
extern "C" void kernel_launch(void* const* d_in, const int* in_sizes, int n_in,
                              void* d_out, int out_size, void* d_ws,
                              size_t ws_size, hipStream_t stream) {
  const float* body = (const float*)d_in[0];
  const float* face = (const float*)d_in[1];
  const int* pose = (const int*)d_in[2];
  const float* A = (const float*)d_in[3];
  const float* W1 = (const float*)d_in[4];
  const float* b1 = (const float*)d_in[5];
  const float* W2 = (const float*)d_in[6];
  const float* b2 = (const float*)d_in[7];
  const float* Wl = (const float*)d_in[8];
  const float* bl = (const float*)d_in[9];
  const float* gamma = (const float*)d_in[10];
  const float* beta = (const float*)d_in[11];
  float* out = (float*)d_out;

  float* ws = (float*)d_ws;
  float* pooled = ws;                       // [512][2048]
  float* bmean = pooled + B_ * C_;          // [512][2048]
  float* h = bmean + B_ * C_;               // [512][128]
  float* gap = h + B_ * HID_;               // [512][2048]
  float* z = gap + B_ * C_;                 // [512][51]
  float* W2T = z + B_ * NATTR_;             // [128][2048]

  fused_pool<<<dim3(8192), dim3(256), 0, stream>>>(body, face, A, pooled,
                                                   bmean);
  w2t_kernel<<<dim3(64), dim3(256), 0, stream>>>(W2, W2T);
  mlp1<<<dim3(512), dim3(256), 0, stream>>>(pooled, W1, b1, h);
  mlp2_t<<<dim3(1024), dim3(256), 0, stream>>>(h, W2T, b2, bmean, pose, gap);
  logits_k<<<dim3(256), dim3(256), 0, stream>>>(gap, Wl, bl, z);
  bn_kernel<<<dim3(NATTR_), dim3(512), 0, stream>>>(z, gamma, beta, out);
}